// Round 8
// baseline (588.009 us; speedup 1.0000x reference)
//
#include <hip/hip_runtime.h>
#include <hip/hip_bf16.h>
#include <math.h>
#include <stdint.h>

#define N_NODES 50000
#define N_EDGES 800000
#define E_TOT   (N_EDGES + N_NODES)   // 850000 with self loops
#define IN_CH   128
#define HID     64
#define NHEAD   8
#define C       512                   // NHEAD*HID
#define NEG_SLOPE 0.2f
#define BN_EPS    1e-5f
#define SM_EPS    1e-16f
#define SCAN_B    196                 // ceil(N_NODES/256)
#define STAT_B    256                 // bn_stats blocks

typedef __attribute__((ext_vector_type(8))) short bf16x8;
typedef __attribute__((ext_vector_type(4))) float f32x4;

__device__ __forceinline__ float lrelu(float x){ return x > 0.f ? x : NEG_SLOPE * x; }
__device__ __forceinline__ float elu(float x){ return x > 0.f ? x : __expf(x) - 1.f; }
__device__ __forceinline__ float bflo(unsigned u){ return __uint_as_float(u << 16); }
__device__ __forceinline__ float bfhi(unsigned u){ return __uint_as_float(u & 0xffff0000u); }
__device__ __forceinline__ float bfu(unsigned short u){ return __uint_as_float(((unsigned)u) << 16); }
__device__ __forceinline__ unsigned short f2bf(float f){
  unsigned u = __float_as_uint(f);
  unsigned r = u + 0x7fffu + ((u >> 16) & 1u);   // RNE
  return (unsigned short)(r >> 16);
}

// ---------------- edge dtype probe ----------------
__global__ void k_detect(const int* __restrict__ ei, int* flag){
  if (threadIdx.x == 0) {
    int f = 1;
    for (int k = 0; k < 32; k++) if (ei[2*k + 1] != 0) f = 0;  // int64 => high words 0
    *flag = f;
  }
}
// count edges per dst (counts pre-zeroed by memset; self-loops handled analytically in scan3)
__global__ void k_count(const int* __restrict__ ei, const int* __restrict__ flag, int* counts){
  int e = blockIdx.x * 256 + threadIdx.x;
  if (e >= N_EDGES) return;
  int d;
  if (*flag) d = (int)((const long long*)ei)[(size_t)N_EDGES + e];
  else       d = ei[N_EDGES + e];
  atomicAdd(&counts[d], 1);
}

// ---------------- scan1 + scan2 fused (done-counter last-block) ----------------
__global__ void k_scan12(const int* __restrict__ counts, int* __restrict__ excl,
                         int* __restrict__ bsum, int* done, int* __restrict__ bsum_s){
  __shared__ int s[256];
  __shared__ int isLast;
  int tid = threadIdx.x;
  int i = blockIdx.x * 256 + tid;
  int v = (i < N_NODES) ? counts[i] : 0;
  s[tid] = v; __syncthreads();
#pragma unroll
  for (int d = 1; d < 256; d <<= 1) {
    int t = (tid >= d) ? s[tid - d] : 0;
    __syncthreads(); s[tid] += t; __syncthreads();
  }
  if (i < N_NODES) excl[i] = s[tid] - v;
  if (tid == 255) bsum[blockIdx.x] = s[255];
  __threadfence();
  if (tid == 0) isLast = (atomicAdd(done, 1) == gridDim.x - 1);
  __syncthreads();
  if (isLast) {
    __threadfence();
    int bv = (tid < SCAN_B) ? bsum[tid] : 0;
    s[tid] = bv; __syncthreads();
#pragma unroll
    for (int d = 1; d < 256; d <<= 1) {
      int t = (tid >= d) ? s[tid - d] : 0;
      __syncthreads(); s[tid] += t; __syncthreads();
    }
    if (tid < SCAN_B) bsum_s[tid] = s[tid] - bv;
  }
}
// scan3: off[i] = edge_excl[i] + i (self loops analytic); place self-loop; cursor past it
__global__ void k_scan3(const int* __restrict__ excl, const int* __restrict__ bsum_s,
                        int* __restrict__ off, int* __restrict__ cursor, int* __restrict__ csr){
  int i = blockIdx.x * 256 + threadIdx.x;
  if (i < N_NODES) {
    int o = excl[i] + bsum_s[blockIdx.x] + i;
    off[i] = o; cursor[i] = o + 1; csr[o] = i;
  }
  if (i == 0) off[N_NODES] = E_TOT;
}
__global__ void k_scatter_edges(const int* __restrict__ ei, const int* __restrict__ flag,
                                int* cursor, int* __restrict__ csr_src){
  int e = blockIdx.x * 256 + threadIdx.x;
  if (e >= N_EDGES) return;
  int s, d;
  if (*flag) {
    const long long* e64 = (const long long*)ei;
    s = (int)e64[e];
    d = (int)e64[(size_t)N_EDGES + e];
  } else {
    s = ei[e];
    d = ei[N_EDGES + e];
  }
  int p = atomicAdd(&cursor[d], 1);
  csr_src[p] = s;
}

// ---------------- W0,W1 -> bf16 transposed [h][c][k] (one kernel) ----------------
__global__ void k_transpose_both(const float* __restrict__ W0, const float* __restrict__ W1,
                                 unsigned short* __restrict__ bt0, unsigned short* __restrict__ bt1){
  int i = blockIdx.x * 256 + threadIdx.x;       // 0 .. 98303
  if (i < 65536) {                              // W0: K=128
    int k = i & 127; int rem = i >> 7; int c = rem & 63; int h = rem >> 6;
    bt0[i] = f2bf(W0[((size_t)h * IN_CH + k) * 64 + c]);
  } else {
    int j = i - 65536;                          // W1: K=64
    int k = j & 63; int rem = j >> 6; int c = rem & 63; int h = rem >> 6;
    bt1[j] = f2bf(W1[((size_t)h * HID + k) * 64 + c]);
  }
}

// ---------------- MFMA GEMM0: X fp32 @ W0, all 8 heads per block ----------------
__global__ __launch_bounds__(256) void k_gemm0(const float* __restrict__ X,
                                               const unsigned short* __restrict__ Bt,   // [h][64][128]
                                               const float* __restrict__ a_src,
                                               const float* __restrict__ a_dst,
                                               unsigned short* __restrict__ H16,
                                               float* __restrict__ s_src,
                                               float* __restrict__ s_dst){
  __shared__ unsigned short LA[64 * 136];
  __shared__ unsigned short LB[64 * 136];
  int r0 = blockIdx.x * 64;
  int tid = threadIdx.x;
#pragma unroll
  for (int i = 0; i < 4; i++) {
    int idx = tid + i * 256;
    int r = idx >> 4, l16 = idx & 15;
    float4 u0 = make_float4(0.f,0.f,0.f,0.f), u1 = u0;
    if (r0 + r < N_NODES) {
      const float* xp = &X[(size_t)(r0 + r) * IN_CH + l16 * 8];
      u0 = *reinterpret_cast<const float4*>(xp);
      u1 = *reinterpret_cast<const float4*>(xp + 4);
    }
    ushort4 p0, p1;
    p0.x = f2bf(u0.x); p0.y = f2bf(u0.y); p0.z = f2bf(u0.z); p0.w = f2bf(u0.w);
    p1.x = f2bf(u1.x); p1.y = f2bf(u1.y); p1.z = f2bf(u1.z); p1.w = f2bf(u1.w);
    *reinterpret_cast<ushort4*>(&LA[r * 136 + l16 * 8]) = p0;
    *reinterpret_cast<ushort4*>(&LA[r * 136 + l16 * 8 + 4]) = p1;
  }
  int w = tid >> 6, l = tid & 63;
  int lr = l & 15, lg = l >> 4;
  for (int h = 0; h < NHEAD; h++) {
    __syncthreads();
#pragma unroll
    for (int i = 0; i < 4; i++) {
      int idx = tid + i * 256;
      int c = idx >> 4, l16 = idx & 15;
      uint4 v = *reinterpret_cast<const uint4*>(&Bt[(size_t)h * 8192 + c * 128 + l16 * 8]);
      *reinterpret_cast<uint4*>(&LB[c * 136 + l16 * 8]) = v;
    }
    __syncthreads();
    f32x4 acc[4] = {};
#pragma unroll
    for (int kf = 0; kf < 4; kf++) {
      bf16x8 af = *reinterpret_cast<const bf16x8*>(&LA[(w * 16 + lr) * 136 + kf * 32 + lg * 8]);
#pragma unroll
      for (int cf = 0; cf < 4; cf++) {
        bf16x8 bfr = *reinterpret_cast<const bf16x8*>(&LB[(cf * 16 + lr) * 136 + kf * 32 + lg * 8]);
        acc[cf] = __builtin_amdgcn_mfma_f32_16x16x32_bf16(af, bfr, acc[cf], 0, 0, 0);
      }
    }
#pragma unroll
    for (int cf = 0; cf < 4; cf++)
#pragma unroll
      for (int rr = 0; rr < 4; rr++) {
        int gr = r0 + w * 16 + lg * 4 + rr;
        if (gr < N_NODES)
          H16[(size_t)gr * C + h * HID + cf * 16 + lr] = f2bf(acc[cf][rr]);
      }
    float ps[4] = {}, pd[4] = {};
#pragma unroll
    for (int cf = 0; cf < 4; cf++) {
      float as_ = a_src[h * HID + cf * 16 + lr];
      float ad_ = a_dst[h * HID + cf * 16 + lr];
#pragma unroll
      for (int rr = 0; rr < 4; rr++) { ps[rr] += acc[cf][rr] * as_; pd[rr] += acc[cf][rr] * ad_; }
    }
#pragma unroll
    for (int rr = 0; rr < 4; rr++)
#pragma unroll
      for (int o = 1; o < 16; o <<= 1) { ps[rr] += __shfl_xor(ps[rr], o, 64); pd[rr] += __shfl_xor(pd[rr], o, 64); }
    if (lr == 0) {
#pragma unroll
      for (int rr = 0; rr < 4; rr++) {
        int gr = r0 + w * 16 + lg * 4 + rr;
        if (gr < N_NODES) { s_src[gr * NHEAD + h] = ps[rr]; s_dst[gr * NHEAD + h] = pd[rr]; }
      }
    }
  }
}

// ---------------- MFMA GEMM1: elu(bn(Hprev bf16)) @ W1 -> H16 bf16 + s scores ----------------
__global__ __launch_bounds__(256) void k_gemm1(const unsigned short* __restrict__ Hb,
                                               const unsigned short* __restrict__ Bt,   // [h][64][64]
                                               const float* __restrict__ scale,
                                               const float* __restrict__ shift,
                                               const float* __restrict__ a_src,
                                               const float* __restrict__ a_dst,
                                               unsigned short* __restrict__ H16,
                                               float* __restrict__ s_src,
                                               float* __restrict__ s_dst){
  __shared__ unsigned short LA[64 * 72];
  __shared__ unsigned short LB[64 * 72];
  int r0 = blockIdx.x * 64, h = blockIdx.y;
  int tid = threadIdx.x;
#pragma unroll
  for (int i = 0; i < 4; i++) {
    int idx = tid + i * 256;
    int r = idx >> 4, l16 = idx & 15;
    ushort4 hv = make_ushort4(0, 0, 0, 0);
    if (r0 + r < N_NODES)
      hv = *reinterpret_cast<const ushort4*>(&Hb[(size_t)(r0 + r) * C + h * HID + l16 * 4]);
    float4 sc = *reinterpret_cast<const float4*>(&scale[h * HID + l16 * 4]);
    float4 sh = *reinterpret_cast<const float4*>(&shift[h * HID + l16 * 4]);
    ushort4 p;
    p.x = f2bf(elu(sc.x * bfu(hv.x) + sh.x));
    p.y = f2bf(elu(sc.y * bfu(hv.y) + sh.y));
    p.z = f2bf(elu(sc.z * bfu(hv.z) + sh.z));
    p.w = f2bf(elu(sc.w * bfu(hv.w) + sh.w));
    *reinterpret_cast<ushort4*>(&LA[r * 72 + l16 * 4]) = p;
  }
#pragma unroll
  for (int i = 0; i < 2; i++) {
    int idx = tid + i * 256;
    int c = idx >> 3, l8 = idx & 7;
    uint4 v = *reinterpret_cast<const uint4*>(&Bt[(size_t)h * 4096 + c * 64 + l8 * 8]);
    *reinterpret_cast<uint4*>(&LB[c * 72 + l8 * 8]) = v;
  }
  __syncthreads();
  int w = tid >> 6, l = tid & 63;
  int lr = l & 15, lg = l >> 4;
  f32x4 acc[4] = {};
#pragma unroll
  for (int kf = 0; kf < 2; kf++) {
    bf16x8 af = *reinterpret_cast<const bf16x8*>(&LA[(w * 16 + lr) * 72 + kf * 32 + lg * 8]);
#pragma unroll
    for (int cf = 0; cf < 4; cf++) {
      bf16x8 bfr = *reinterpret_cast<const bf16x8*>(&LB[(cf * 16 + lr) * 72 + kf * 32 + lg * 8]);
      acc[cf] = __builtin_amdgcn_mfma_f32_16x16x32_bf16(af, bfr, acc[cf], 0, 0, 0);
    }
  }
#pragma unroll
  for (int cf = 0; cf < 4; cf++)
#pragma unroll
    for (int rr = 0; rr < 4; rr++) {
      int gr = r0 + w * 16 + lg * 4 + rr;
      if (gr < N_NODES)
        H16[(size_t)gr * C + h * HID + cf * 16 + lr] = f2bf(acc[cf][rr]);
    }
  float ps[4] = {}, pd[4] = {};
#pragma unroll
  for (int cf = 0; cf < 4; cf++) {
    float as_ = a_src[h * HID + cf * 16 + lr];
    float ad_ = a_dst[h * HID + cf * 16 + lr];
#pragma unroll
    for (int rr = 0; rr < 4; rr++) { ps[rr] += acc[cf][rr] * as_; pd[rr] += acc[cf][rr] * ad_; }
  }
#pragma unroll
  for (int rr = 0; rr < 4; rr++)
#pragma unroll
    for (int o = 1; o < 16; o <<= 1) { ps[rr] += __shfl_xor(ps[rr], o, 64); pd[rr] += __shfl_xor(pd[rr], o, 64); }
  if (lr == 0) {
#pragma unroll
    for (int rr = 0; rr < 4; rr++) {
      int gr = r0 + w * 16 + lg * 4 + rr;
      if (gr < N_NODES) { s_src[gr * NHEAD + h] = ps[rr]; s_dst[gr * NHEAD + h] = pd[rr]; }
    }
  }
}

// ---------------- single-pass softmax + aggregation (measured-best: shfl, unroll 2) ----------------
__global__ __launch_bounds__(256) void k_aggregate(const unsigned short* __restrict__ H16,
                                                   const float* __restrict__ s_src,
                                                   const float* __restrict__ s_dst,
                                                   const int* __restrict__ off,
                                                   const int* __restrict__ csr,
                                                   const float* __restrict__ bias,
                                                   unsigned short* __restrict__ HoutB){
  __shared__ float alds[4][64][8];
  int wv = threadIdx.x >> 6, lane = threadIdx.x & 63;
  int n = blockIdx.x * 4 + wv;
  if (n >= N_NODES) return;
  int e0 = off[n], deg = off[n + 1] - e0;
  int hsel = lane >> 3;

  float sd[NHEAD];
#pragma unroll
  for (int h = 0; h < NHEAD; h++) sd[h] = s_dst[n * NHEAD + h];

  float acc[8] = {};
  float dnl[NHEAD] = {};

  for (int base = 0; base < deg; base += 64) {
    int e = base + lane;
    int cnt = min(64, deg - base);
    int s_reg = 0;
    if (e < deg) {
      s_reg = csr[e0 + e];
      const float4* sp = reinterpret_cast<const float4*>(&s_src[s_reg * NHEAD]);
      float4 s01 = sp[0], s23 = sp[1];
      float sv[8] = { s01.x, s01.y, s01.z, s01.w, s23.x, s23.y, s23.z, s23.w };
#pragma unroll
      for (int h = 0; h < NHEAD; h++) {
        float ex = __expf(lrelu(sv[h] + sd[h]));
        dnl[h] += ex;
        alds[wv][lane][h] = ex;
      }
    }
#pragma unroll 2
    for (int j = 0; j < cnt; j++) {
      int s = __shfl(s_reg, j, 64);
      float a = alds[wv][j][hsel];
      const uint4* rp = reinterpret_cast<const uint4*>(H16 + (size_t)s * C);
      uint4 v = rp[lane];
      acc[0] += a * bflo(v.x); acc[1] += a * bfhi(v.x);
      acc[2] += a * bflo(v.y); acc[3] += a * bfhi(v.y);
      acc[4] += a * bflo(v.z); acc[5] += a * bfhi(v.z);
      acc[6] += a * bflo(v.w); acc[7] += a * bfhi(v.w);
    }
  }

  float mydn = 0.f;
#pragma unroll
  for (int h = 0; h < NHEAD; h++) {
    float d = dnl[h];
#pragma unroll
    for (int o = 32; o; o >>= 1) d += __shfl_xor(d, o, 64);
    if (hsel == h) mydn = d;
  }
  float inv = 1.f / (mydn + SM_EPS);

  const float* bp = bias + lane * 8;
  ushort4 p0, p1;
  p0.x = f2bf(acc[0]*inv + bp[0]); p0.y = f2bf(acc[1]*inv + bp[1]);
  p0.z = f2bf(acc[2]*inv + bp[2]); p0.w = f2bf(acc[3]*inv + bp[3]);
  p1.x = f2bf(acc[4]*inv + bp[4]); p1.y = f2bf(acc[5]*inv + bp[5]);
  p1.z = f2bf(acc[6]*inv + bp[6]); p1.w = f2bf(acc[7]*inv + bp[7]);
  unsigned short* op = HoutB + (size_t)n * C + lane * 8;
  *reinterpret_cast<ushort4*>(op) = p0;
  *reinterpret_cast<ushort4*>(op + 4) = p1;
}

// ---------------- BatchNorm stats + finalize (done-counter last-block) ----------------
__global__ __launch_bounds__(256) void k_bn_stats(const unsigned short* __restrict__ Hb,
                                                  float* __restrict__ partial, int* done2,
                                                  const float* __restrict__ gamma,
                                                  const float* __restrict__ beta,
                                                  float* __restrict__ scale,
                                                  float* __restrict__ shift){
  __shared__ float red[4][64][16];
  __shared__ int isLast;
  int tid = threadIdx.x, w = tid >> 6, c64 = tid & 63;
  float s[8] = {}, q[8] = {};
  for (int r = blockIdx.x * 4 + w; r < N_NODES; r += gridDim.x * 4) {
    uint4 v = *reinterpret_cast<const uint4*>(&Hb[(size_t)r * C + c64 * 8]);
    float f[8] = { bflo(v.x), bfhi(v.x), bflo(v.y), bfhi(v.y),
                   bflo(v.z), bfhi(v.z), bflo(v.w), bfhi(v.w) };
#pragma unroll
    for (int k = 0; k < 8; k++) { s[k] += f[k]; q[k] += f[k] * f[k]; }
  }
#pragma unroll
  for (int k = 0; k < 8; k++) { red[w][c64][k] = s[k]; red[w][c64][k + 8] = q[k]; }
  __syncthreads();
  if (w == 0) {
#pragma unroll
    for (int k = 0; k < 8; k++) {
      float ss = red[0][c64][k] + red[1][c64][k] + red[2][c64][k] + red[3][c64][k];
      float qq = red[0][c64][k+8] + red[1][c64][k+8] + red[2][c64][k+8] + red[3][c64][k+8];
      partial[(size_t)blockIdx.x * 1024 + c64 * 8 + k] = ss;
      partial[(size_t)blockIdx.x * 1024 + 512 + c64 * 8 + k] = qq;
    }
  }
  __threadfence();
  if (tid == 0) isLast = (atomicAdd(done2, 1) == gridDim.x - 1);
  __syncthreads();
  if (isLast) {
    __threadfence();
#pragma unroll
    for (int cc = 0; cc < 2; cc++) {
      int c = tid + cc * 256;
      float ssum = 0.f, qsum = 0.f;
      for (int b = 0; b < STAT_B; b++) {
        ssum += partial[(size_t)b * 1024 + c];
        qsum += partial[(size_t)b * 1024 + 512 + c];
      }
      float mean = ssum * (1.f / N_NODES);
      float var  = qsum * (1.f / N_NODES) - mean * mean;
      float sc = gamma[c] * rsqrtf(var + BN_EPS);
      scale[c] = sc;
      shift[c] = beta[c] - mean * sc;
    }
    if (tid == 0) *done2 = 0;   // reset for the next bn_stats launch
  }
}

// ---------------- final: out = elu(bn(Hb)) @ Wc + bc ----------------
__global__ __launch_bounds__(256) void k_final(const unsigned short* __restrict__ Hb,
                                               const float* __restrict__ scale,
                                               const float* __restrict__ shift,
                                               const float* __restrict__ Wc,
                                               const float* __restrict__ bc,
                                               float* __restrict__ out){
  int wave = threadIdx.x >> 6, lane = threadIdx.x & 63;
  int n = blockIdx.x * 4 + wave;
  if (n >= N_NODES) return;
  uint4 v = *reinterpret_cast<const uint4*>(&Hb[(size_t)n * C + lane * 8]);
  float f[8] = { bflo(v.x), bfhi(v.x), bflo(v.y), bfhi(v.y),
                 bflo(v.z), bfhi(v.z), bflo(v.w), bfhi(v.w) };
  float4 sc0 = *reinterpret_cast<const float4*>(&scale[lane * 8]);
  float4 sc1 = *reinterpret_cast<const float4*>(&scale[lane * 8 + 4]);
  float4 sh0 = *reinterpret_cast<const float4*>(&shift[lane * 8]);
  float4 sh1 = *reinterpret_cast<const float4*>(&shift[lane * 8 + 4]);
  float scv[8] = { sc0.x, sc0.y, sc0.z, sc0.w, sc1.x, sc1.y, sc1.z, sc1.w };
  float shv[8] = { sh0.x, sh0.y, sh0.z, sh0.w, sh1.x, sh1.y, sh1.z, sh1.w };
  float a0 = 0.f, a1 = 0.f;
#pragma unroll
  for (int k = 0; k < 8; k++) {
    float t = elu(scv[k] * f[k] + shv[k]);
    int ch = lane * 8 + k;
    a0 += t * Wc[ch * 2 + 0];
    a1 += t * Wc[ch * 2 + 1];
  }
#pragma unroll
  for (int o = 32; o; o >>= 1) { a0 += __shfl_xor(a0, o, 64); a1 += __shfl_xor(a1, o, 64); }
  if (lane == 0) { out[n * 2 + 0] = a0 + bc[0]; out[n * 2 + 1] = a1 + bc[1]; }
}

extern "C" void kernel_launch(void* const* d_in, const int* in_sizes, int n_in,
                              void* d_out, int out_size, void* d_ws, size_t ws_size,
                              hipStream_t stream) {
  const float* x      = (const float*)d_in[0];
  const int*   ei     = (const int*)d_in[1];
  const float* W0     = (const float*)d_in[2];
  const float* a_src0 = (const float*)d_in[3];
  const float* a_dst0 = (const float*)d_in[4];
  const float* b0     = (const float*)d_in[5];
  const float* gamma0 = (const float*)d_in[6];
  const float* beta0  = (const float*)d_in[7];
  const float* W1     = (const float*)d_in[8];
  const float* a_src1 = (const float*)d_in[9];
  const float* a_dst1 = (const float*)d_in[10];
  const float* b1     = (const float*)d_in[11];
  const float* gamma1 = (const float*)d_in[12];
  const float* beta1  = (const float*)d_in[13];
  const float* Wc     = (const float*)d_in[14];
  const float* bc     = (const float*)d_in[15];
  float* out = (float*)d_out;

  char* ws = (char*)d_ws;
  size_t o = 0;
  auto alloc = [&](size_t bytes) { char* p = ws + o; o = (o + bytes + 255) & ~(size_t)255; return p; };
  int*   flag    = (int*)  alloc(4);
  int*   done    = (int*)  alloc(8);          // [0]=scan12, [1]=bn_stats
  int*   counts  = (int*)  alloc((size_t)N_NODES * 4);
  int*   excl    = (int*)  alloc((size_t)N_NODES * 4);
  int*   bsum    = (int*)  alloc(256 * 4);
  int*   bsum_s  = (int*)  alloc(256 * 4);
  int*   off     = (int*)  alloc((size_t)(N_NODES + 1) * 4);
  int*   cursor  = (int*)  alloc((size_t)N_NODES * 4);
  int*   csr     = (int*)  alloc((size_t)E_TOT * 4);
  float* s_src   = (float*)alloc((size_t)N_NODES * NHEAD * 4);
  float* s_dst   = (float*)alloc((size_t)N_NODES * NHEAD * 4);
  float* partial = (float*)alloc((size_t)STAT_B * 1024 * 4);
  float* scale   = (float*)alloc(C * 4);
  float* shift   = (float*)alloc(C * 4);
  unsigned short* bt0  = (unsigned short*)alloc((size_t)NHEAD * HID * IN_CH * 2);
  unsigned short* bt1  = (unsigned short*)alloc((size_t)NHEAD * HID * HID * 2);
  unsigned short* h16a = (unsigned short*)alloc((size_t)N_NODES * C * 2);
  unsigned short* h16b = (unsigned short*)alloc((size_t)N_NODES * C * 2);

  const int GE = (N_EDGES + 255) / 256;      // 3125
  const int GN = (N_NODES + 255) / 256;      // 196
  const int GW = (N_NODES + 3) / 4;          // 12500
  const int GR = (N_NODES + 63) / 64;        // 782

  // CSR build
  hipMemsetAsync(counts, 0, (size_t)N_NODES * 4, stream);
  hipMemsetAsync(done, 0, 8, stream);
  k_detect<<<1, 64, 0, stream>>>(ei, flag);
  k_count<<<GE, 256, 0, stream>>>(ei, flag, counts);
  k_transpose_both<<<384, 256, 0, stream>>>(W0, W1, bt0, bt1);
  k_scan12<<<GN, 256, 0, stream>>>(counts, excl, bsum, &done[0], bsum_s);
  k_scan3<<<GN, 256, 0, stream>>>(excl, bsum_s, off, cursor, csr);
  k_scatter_edges<<<GE, 256, 0, stream>>>(ei, flag, cursor, csr);

  // ----- layer 0 -----
  k_gemm0<<<GR, 256, 0, stream>>>(x, bt0, a_src0, a_dst0, h16a, s_src, s_dst);
  k_aggregate<<<GW, 256, 0, stream>>>(h16a, s_src, s_dst, off, csr, b0, h16b);
  k_bn_stats<<<STAT_B, 256, 0, stream>>>(h16b, partial, &done[1], gamma0, beta0, scale, shift);

  // ----- layer 1 (BN0+ELU fused into GEMM1 A-staging) -----
  k_gemm1<<<dim3(GR, NHEAD), 256, 0, stream>>>(h16b, bt1, scale, shift, a_src1, a_dst1, h16a, s_src, s_dst);
  k_aggregate<<<GW, 256, 0, stream>>>(h16a, s_src, s_dst, off, csr, b1, h16b);
  k_bn_stats<<<STAT_B, 256, 0, stream>>>(h16b, partial, &done[1], gamma1, beta1, scale, shift);

  // ----- classifier (BN1+ELU fused) -----
  k_final<<<GW, 256, 0, stream>>>(h16b, scale, shift, Wc, bc, out);
}

// Round 9
// 513.666 us; speedup vs baseline: 1.1447x; 1.1447x over previous
//
#include <hip/hip_runtime.h>
#include <hip/hip_bf16.h>
#include <math.h>
#include <stdint.h>

#define N_NODES 50000
#define N_EDGES 800000
#define E_TOT   (N_EDGES + N_NODES)   // 850000 with self loops
#define IN_CH   128
#define HID     64
#define NHEAD   8
#define C       512                   // NHEAD*HID
#define NEG_SLOPE 0.2f
#define BN_EPS    1e-5f
#define SM_EPS    1e-16f
#define SCAN_B    196                 // ceil(N_NODES/256)
#define STAT_B    256                 // bn_stats blocks

typedef __attribute__((ext_vector_type(8))) short bf16x8;
typedef __attribute__((ext_vector_type(4))) float f32x4;

__device__ __forceinline__ float lrelu(float x){ return x > 0.f ? x : NEG_SLOPE * x; }
__device__ __forceinline__ float elu(float x){ return x > 0.f ? x : __expf(x) - 1.f; }
__device__ __forceinline__ float bflo(unsigned u){ return __uint_as_float(u << 16); }
__device__ __forceinline__ float bfhi(unsigned u){ return __uint_as_float(u & 0xffff0000u); }
__device__ __forceinline__ float bfu(unsigned short u){ return __uint_as_float(((unsigned)u) << 16); }
__device__ __forceinline__ unsigned short f2bf(float f){
  unsigned u = __float_as_uint(f);
  unsigned r = u + 0x7fffu + ((u >> 16) & 1u);   // RNE
  return (unsigned short)(r >> 16);
}

// ---------------- init: counts=1 (self loop), detect edge dtype, zero done ----------------
__global__ void k_init(const int* __restrict__ ei, int* counts, int* flag, int* done){
  int i = blockIdx.x * 256 + threadIdx.x;
  if (i < N_NODES) counts[i] = 1;
  if (blockIdx.x == 0 && threadIdx.x == 0) {
    int f = 1;
    for (int k = 0; k < 32; k++) if (ei[2*k + 1] != 0) f = 0;  // int64 => high words 0
    *flag = f;
    *done = 0;
  }
}
__global__ void k_extract_count(const int* __restrict__ ei, const int* __restrict__ flag,
                                int* __restrict__ src32, int* __restrict__ dst32,
                                int* counts){
  int e = blockIdx.x * 256 + threadIdx.x;
  if (e >= N_EDGES) return;
  int s, d;
  if (*flag) {
    const long long* e64 = (const long long*)ei;
    s = (int)e64[e];
    d = (int)e64[(size_t)N_EDGES + e];
  } else {
    s = ei[e];
    d = ei[N_EDGES + e];
  }
  src32[e] = s; dst32[e] = d;
  atomicAdd(&counts[d], 1);
}

// ---------------- scan1 + scan2 fused (done-counter last-block) ----------------
__global__ void k_scan12(const int* __restrict__ counts, int* __restrict__ excl,
                         int* __restrict__ bsum, int* done, int* __restrict__ bsum_s){
  __shared__ int s[256];
  __shared__ int isLast;
  int tid = threadIdx.x;
  int i = blockIdx.x * 256 + tid;
  int v = (i < N_NODES) ? counts[i] : 0;
  s[tid] = v; __syncthreads();
#pragma unroll
  for (int d = 1; d < 256; d <<= 1) {
    int t = (tid >= d) ? s[tid - d] : 0;
    __syncthreads(); s[tid] += t; __syncthreads();
  }
  if (i < N_NODES) excl[i] = s[tid] - v;
  if (tid == 255) bsum[blockIdx.x] = s[255];
  __threadfence();
  if (tid == 0) isLast = (atomicAdd(done, 1) == gridDim.x - 1);
  __syncthreads();
  if (isLast) {
    __threadfence();
    int bv = (tid < SCAN_B) ? bsum[tid] : 0;
    s[tid] = bv; __syncthreads();
#pragma unroll
    for (int d = 1; d < 256; d <<= 1) {
      int t = (tid >= d) ? s[tid - d] : 0;
      __syncthreads(); s[tid] += t; __syncthreads();
    }
    if (tid < SCAN_B) bsum_s[tid] = s[tid] - bv;
  }
}
// scan3: final offsets; place self-loop at off[i]; cursor past it
__global__ void k_scan3(const int* __restrict__ excl, const int* __restrict__ bsum_s,
                        int* __restrict__ off, int* __restrict__ cursor, int* __restrict__ csr){
  int i = blockIdx.x * 256 + threadIdx.x;
  if (i < N_NODES) {
    int o = excl[i] + bsum_s[blockIdx.x];
    off[i] = o; cursor[i] = o + 1; csr[o] = i;
  }
  if (i == 0) off[N_NODES] = E_TOT;
}
__global__ void k_scatter_edges(const int* __restrict__ src, const int* __restrict__ dst,
                                int* cursor, int* __restrict__ csr_src){
  int e = blockIdx.x * 256 + threadIdx.x;
  if (e < N_EDGES) { int d = dst[e]; int p = atomicAdd(&cursor[d], 1); csr_src[p] = src[e]; }
}

// ---------------- W0,W1 -> bf16 transposed [h][c][k] (one kernel) ----------------
__global__ void k_transpose_both(const float* __restrict__ W0, const float* __restrict__ W1,
                                 unsigned short* __restrict__ bt0, unsigned short* __restrict__ bt1){
  int i = blockIdx.x * 256 + threadIdx.x;       // 0 .. 98303
  if (i < 65536) {                              // W0: K=128
    int k = i & 127; int rem = i >> 7; int c = rem & 63; int h = rem >> 6;
    bt0[i] = f2bf(W0[((size_t)h * IN_CH + k) * 64 + c]);
  } else {
    int j = i - 65536;                          // W1: K=64
    int k = j & 63; int rem = j >> 6; int c = rem & 63; int h = rem >> 6;
    bt1[j] = f2bf(W1[((size_t)h * HID + k) * 64 + c]);
  }
}

// ---------------- MFMA GEMM0: X fp32 @ W0, all 8 heads per block ----------------
__global__ __launch_bounds__(256) void k_gemm0(const float* __restrict__ X,
                                               const unsigned short* __restrict__ Bt,   // [h][64][128]
                                               const float* __restrict__ a_src,
                                               const float* __restrict__ a_dst,
                                               unsigned short* __restrict__ H16,
                                               float* __restrict__ s_src,
                                               float* __restrict__ s_dst){
  __shared__ unsigned short LA[64 * 136];
  __shared__ unsigned short LB[64 * 136];
  int r0 = blockIdx.x * 64;
  int tid = threadIdx.x;
#pragma unroll
  for (int i = 0; i < 4; i++) {
    int idx = tid + i * 256;
    int r = idx >> 4, l16 = idx & 15;
    float4 u0 = make_float4(0.f,0.f,0.f,0.f), u1 = u0;
    if (r0 + r < N_NODES) {
      const float* xp = &X[(size_t)(r0 + r) * IN_CH + l16 * 8];
      u0 = *reinterpret_cast<const float4*>(xp);
      u1 = *reinterpret_cast<const float4*>(xp + 4);
    }
    ushort4 p0, p1;
    p0.x = f2bf(u0.x); p0.y = f2bf(u0.y); p0.z = f2bf(u0.z); p0.w = f2bf(u0.w);
    p1.x = f2bf(u1.x); p1.y = f2bf(u1.y); p1.z = f2bf(u1.z); p1.w = f2bf(u1.w);
    *reinterpret_cast<ushort4*>(&LA[r * 136 + l16 * 8]) = p0;
    *reinterpret_cast<ushort4*>(&LA[r * 136 + l16 * 8 + 4]) = p1;
  }
  int w = tid >> 6, l = tid & 63;
  int lr = l & 15, lg = l >> 4;
  for (int h = 0; h < NHEAD; h++) {
    __syncthreads();
#pragma unroll
    for (int i = 0; i < 4; i++) {
      int idx = tid + i * 256;
      int c = idx >> 4, l16 = idx & 15;
      uint4 v = *reinterpret_cast<const uint4*>(&Bt[(size_t)h * 8192 + c * 128 + l16 * 8]);
      *reinterpret_cast<uint4*>(&LB[c * 136 + l16 * 8]) = v;
    }
    __syncthreads();
    f32x4 acc[4] = {};
#pragma unroll
    for (int kf = 0; kf < 4; kf++) {
      bf16x8 af = *reinterpret_cast<const bf16x8*>(&LA[(w * 16 + lr) * 136 + kf * 32 + lg * 8]);
#pragma unroll
      for (int cf = 0; cf < 4; cf++) {
        bf16x8 bfr = *reinterpret_cast<const bf16x8*>(&LB[(cf * 16 + lr) * 136 + kf * 32 + lg * 8]);
        acc[cf] = __builtin_amdgcn_mfma_f32_16x16x32_bf16(af, bfr, acc[cf], 0, 0, 0);
      }
    }
#pragma unroll
    for (int cf = 0; cf < 4; cf++)
#pragma unroll
      for (int rr = 0; rr < 4; rr++) {
        int gr = r0 + w * 16 + lg * 4 + rr;
        if (gr < N_NODES)
          H16[(size_t)gr * C + h * HID + cf * 16 + lr] = f2bf(acc[cf][rr]);
      }
    float ps[4] = {}, pd[4] = {};
#pragma unroll
    for (int cf = 0; cf < 4; cf++) {
      float as_ = a_src[h * HID + cf * 16 + lr];
      float ad_ = a_dst[h * HID + cf * 16 + lr];
#pragma unroll
      for (int rr = 0; rr < 4; rr++) { ps[rr] += acc[cf][rr] * as_; pd[rr] += acc[cf][rr] * ad_; }
    }
#pragma unroll
    for (int rr = 0; rr < 4; rr++)
#pragma unroll
      for (int o = 1; o < 16; o <<= 1) { ps[rr] += __shfl_xor(ps[rr], o, 64); pd[rr] += __shfl_xor(pd[rr], o, 64); }
    if (lr == 0) {
#pragma unroll
      for (int rr = 0; rr < 4; rr++) {
        int gr = r0 + w * 16 + lg * 4 + rr;
        if (gr < N_NODES) { s_src[gr * NHEAD + h] = ps[rr]; s_dst[gr * NHEAD + h] = pd[rr]; }
      }
    }
  }
}

// ---------------- MFMA GEMM1: elu(bn(Hprev bf16)) @ W1 -> H16 bf16 + s scores ----------------
__global__ __launch_bounds__(256) void k_gemm1(const unsigned short* __restrict__ Hb,
                                               const unsigned short* __restrict__ Bt,   // [h][64][64]
                                               const float* __restrict__ scale,
                                               const float* __restrict__ shift,
                                               const float* __restrict__ a_src,
                                               const float* __restrict__ a_dst,
                                               unsigned short* __restrict__ H16,
                                               float* __restrict__ s_src,
                                               float* __restrict__ s_dst){
  __shared__ unsigned short LA[64 * 72];
  __shared__ unsigned short LB[64 * 72];
  int r0 = blockIdx.x * 64, h = blockIdx.y;
  int tid = threadIdx.x;
#pragma unroll
  for (int i = 0; i < 4; i++) {
    int idx = tid + i * 256;
    int r = idx >> 4, l16 = idx & 15;
    ushort4 hv = make_ushort4(0, 0, 0, 0);
    if (r0 + r < N_NODES)
      hv = *reinterpret_cast<const ushort4*>(&Hb[(size_t)(r0 + r) * C + h * HID + l16 * 4]);
    float4 sc = *reinterpret_cast<const float4*>(&scale[h * HID + l16 * 4]);
    float4 sh = *reinterpret_cast<const float4*>(&shift[h * HID + l16 * 4]);
    ushort4 p;
    p.x = f2bf(elu(sc.x * bfu(hv.x) + sh.x));
    p.y = f2bf(elu(sc.y * bfu(hv.y) + sh.y));
    p.z = f2bf(elu(sc.z * bfu(hv.z) + sh.z));
    p.w = f2bf(elu(sc.w * bfu(hv.w) + sh.w));
    *reinterpret_cast<ushort4*>(&LA[r * 72 + l16 * 4]) = p;
  }
#pragma unroll
  for (int i = 0; i < 2; i++) {
    int idx = tid + i * 256;
    int c = idx >> 3, l8 = idx & 7;
    uint4 v = *reinterpret_cast<const uint4*>(&Bt[(size_t)h * 4096 + c * 64 + l8 * 8]);
    *reinterpret_cast<uint4*>(&LB[c * 72 + l8 * 8]) = v;
  }
  __syncthreads();
  int w = tid >> 6, l = tid & 63;
  int lr = l & 15, lg = l >> 4;
  f32x4 acc[4] = {};
#pragma unroll
  for (int kf = 0; kf < 2; kf++) {
    bf16x8 af = *reinterpret_cast<const bf16x8*>(&LA[(w * 16 + lr) * 72 + kf * 32 + lg * 8]);
#pragma unroll
    for (int cf = 0; cf < 4; cf++) {
      bf16x8 bfr = *reinterpret_cast<const bf16x8*>(&LB[(cf * 16 + lr) * 72 + kf * 32 + lg * 8]);
      acc[cf] = __builtin_amdgcn_mfma_f32_16x16x32_bf16(af, bfr, acc[cf], 0, 0, 0);
    }
  }
#pragma unroll
  for (int cf = 0; cf < 4; cf++)
#pragma unroll
    for (int rr = 0; rr < 4; rr++) {
      int gr = r0 + w * 16 + lg * 4 + rr;
      if (gr < N_NODES)
        H16[(size_t)gr * C + h * HID + cf * 16 + lr] = f2bf(acc[cf][rr]);
    }
  float ps[4] = {}, pd[4] = {};
#pragma unroll
  for (int cf = 0; cf < 4; cf++) {
    float as_ = a_src[h * HID + cf * 16 + lr];
    float ad_ = a_dst[h * HID + cf * 16 + lr];
#pragma unroll
    for (int rr = 0; rr < 4; rr++) { ps[rr] += acc[cf][rr] * as_; pd[rr] += acc[cf][rr] * ad_; }
  }
#pragma unroll
  for (int rr = 0; rr < 4; rr++)
#pragma unroll
    for (int o = 1; o < 16; o <<= 1) { ps[rr] += __shfl_xor(ps[rr], o, 64); pd[rr] += __shfl_xor(pd[rr], o, 64); }
  if (lr == 0) {
#pragma unroll
    for (int rr = 0; rr < 4; rr++) {
      int gr = r0 + w * 16 + lg * 4 + rr;
      if (gr < N_NODES) { s_src[gr * NHEAD + h] = ps[rr]; s_dst[gr * NHEAD + h] = pd[rr]; }
    }
  }
}

// ---------------- single-pass softmax + aggregation (measured-best: shfl, unroll 2) ----------------
__global__ __launch_bounds__(256) void k_aggregate(const unsigned short* __restrict__ H16,
                                                   const float* __restrict__ s_src,
                                                   const float* __restrict__ s_dst,
                                                   const int* __restrict__ off,
                                                   const int* __restrict__ csr,
                                                   const float* __restrict__ bias,
                                                   unsigned short* __restrict__ HoutB){
  __shared__ float alds[4][64][8];
  int wv = threadIdx.x >> 6, lane = threadIdx.x & 63;
  int n = blockIdx.x * 4 + wv;
  if (n >= N_NODES) return;
  int e0 = off[n], deg = off[n + 1] - e0;
  int hsel = lane >> 3;

  float sd[NHEAD];
#pragma unroll
  for (int h = 0; h < NHEAD; h++) sd[h] = s_dst[n * NHEAD + h];

  float acc[8] = {};
  float dnl[NHEAD] = {};

  for (int base = 0; base < deg; base += 64) {
    int e = base + lane;
    int cnt = min(64, deg - base);
    int s_reg = 0;
    if (e < deg) {
      s_reg = csr[e0 + e];
      const float4* sp = reinterpret_cast<const float4*>(&s_src[s_reg * NHEAD]);
      float4 s01 = sp[0], s23 = sp[1];
      float sv[8] = { s01.x, s01.y, s01.z, s01.w, s23.x, s23.y, s23.z, s23.w };
#pragma unroll
      for (int h = 0; h < NHEAD; h++) {
        float ex = __expf(lrelu(sv[h] + sd[h]));
        dnl[h] += ex;
        alds[wv][lane][h] = ex;
      }
    }
#pragma unroll 2
    for (int j = 0; j < cnt; j++) {
      int s = __shfl(s_reg, j, 64);
      float a = alds[wv][j][hsel];
      const uint4* rp = reinterpret_cast<const uint4*>(H16 + (size_t)s * C);
      uint4 v = rp[lane];
      acc[0] += a * bflo(v.x); acc[1] += a * bfhi(v.x);
      acc[2] += a * bflo(v.y); acc[3] += a * bfhi(v.y);
      acc[4] += a * bflo(v.z); acc[5] += a * bfhi(v.z);
      acc[6] += a * bflo(v.w); acc[7] += a * bfhi(v.w);
    }
  }

  float mydn = 0.f;
#pragma unroll
  for (int h = 0; h < NHEAD; h++) {
    float d = dnl[h];
#pragma unroll
    for (int o = 32; o; o >>= 1) d += __shfl_xor(d, o, 64);
    if (hsel == h) mydn = d;
  }
  float inv = 1.f / (mydn + SM_EPS);

  const float* bp = bias + lane * 8;
  ushort4 p0, p1;
  p0.x = f2bf(acc[0]*inv + bp[0]); p0.y = f2bf(acc[1]*inv + bp[1]);
  p0.z = f2bf(acc[2]*inv + bp[2]); p0.w = f2bf(acc[3]*inv + bp[3]);
  p1.x = f2bf(acc[4]*inv + bp[4]); p1.y = f2bf(acc[5]*inv + bp[5]);
  p1.z = f2bf(acc[6]*inv + bp[6]); p1.w = f2bf(acc[7]*inv + bp[7]);
  unsigned short* op = HoutB + (size_t)n * C + lane * 8;
  *reinterpret_cast<ushort4*>(op) = p0;
  *reinterpret_cast<ushort4*>(op + 4) = p1;
}

// ---------------- BatchNorm stats: per-block partials (no atomics) ----------------
__global__ __launch_bounds__(256) void k_bn_stats(const unsigned short* __restrict__ Hb,
                                                  float* __restrict__ partial){
  __shared__ float red[4][64][16];
  int tid = threadIdx.x, w = tid >> 6, c64 = tid & 63;
  float s[8] = {}, q[8] = {};
  for (int r = blockIdx.x * 4 + w; r < N_NODES; r += gridDim.x * 4) {
    uint4 v = *reinterpret_cast<const uint4*>(&Hb[(size_t)r * C + c64 * 8]);
    float f[8] = { bflo(v.x), bfhi(v.x), bflo(v.y), bfhi(v.y),
                   bflo(v.z), bfhi(v.z), bflo(v.w), bfhi(v.w) };
#pragma unroll
    for (int k = 0; k < 8; k++) { s[k] += f[k]; q[k] += f[k] * f[k]; }
  }
#pragma unroll
  for (int k = 0; k < 8; k++) { red[w][c64][k] = s[k]; red[w][c64][k + 8] = q[k]; }
  __syncthreads();
  if (w == 0) {
#pragma unroll
    for (int k = 0; k < 8; k++) {
      float ss = red[0][c64][k] + red[1][c64][k] + red[2][c64][k] + red[3][c64][k];
      float qq = red[0][c64][k+8] + red[1][c64][k+8] + red[2][c64][k+8] + red[3][c64][k+8];
      partial[(size_t)blockIdx.x * 1024 + c64 * 8 + k] = ss;
      partial[(size_t)blockIdx.x * 1024 + 512 + c64 * 8 + k] = qq;
    }
  }
}
__global__ void k_bn_finalize(const float* __restrict__ partial, const float* __restrict__ gamma,
                              const float* __restrict__ beta, float* __restrict__ scale,
                              float* __restrict__ shift){
  int c = threadIdx.x;  // 512 threads
  float s = 0.f, q = 0.f;
  for (int b = 0; b < STAT_B; b++) {
    s += partial[(size_t)b * 1024 + c];
    q += partial[(size_t)b * 1024 + 512 + c];
  }
  float mean = s * (1.f / N_NODES);
  float var  = q * (1.f / N_NODES) - mean * mean;
  float sc = gamma[c] * rsqrtf(var + BN_EPS);
  scale[c] = sc;
  shift[c] = beta[c] - mean * sc;
}

// ---------------- final: out = elu(bn(Hb)) @ Wc + bc ----------------
__global__ __launch_bounds__(256) void k_final(const unsigned short* __restrict__ Hb,
                                               const float* __restrict__ scale,
                                               const float* __restrict__ shift,
                                               const float* __restrict__ Wc,
                                               const float* __restrict__ bc,
                                               float* __restrict__ out){
  int wave = threadIdx.x >> 6, lane = threadIdx.x & 63;
  int n = blockIdx.x * 4 + wave;
  if (n >= N_NODES) return;
  uint4 v = *reinterpret_cast<const uint4*>(&Hb[(size_t)n * C + lane * 8]);
  float f[8] = { bflo(v.x), bfhi(v.x), bflo(v.y), bfhi(v.y),
                 bflo(v.z), bfhi(v.z), bflo(v.w), bfhi(v.w) };
  float4 sc0 = *reinterpret_cast<const float4*>(&scale[lane * 8]);
  float4 sc1 = *reinterpret_cast<const float4*>(&scale[lane * 8 + 4]);
  float4 sh0 = *reinterpret_cast<const float4*>(&shift[lane * 8]);
  float4 sh1 = *reinterpret_cast<const float4*>(&shift[lane * 8 + 4]);
  float scv[8] = { sc0.x, sc0.y, sc0.z, sc0.w, sc1.x, sc1.y, sc1.z, sc1.w };
  float shv[8] = { sh0.x, sh0.y, sh0.z, sh0.w, sh1.x, sh1.y, sh1.z, sh1.w };
  float a0 = 0.f, a1 = 0.f;
#pragma unroll
  for (int k = 0; k < 8; k++) {
    float t = elu(scv[k] * f[k] + shv[k]);
    int ch = lane * 8 + k;
    a0 += t * Wc[ch * 2 + 0];
    a1 += t * Wc[ch * 2 + 1];
  }
#pragma unroll
  for (int o = 32; o; o >>= 1) { a0 += __shfl_xor(a0, o, 64); a1 += __shfl_xor(a1, o, 64); }
  if (lane == 0) { out[n * 2 + 0] = a0 + bc[0]; out[n * 2 + 1] = a1 + bc[1]; }
}

extern "C" void kernel_launch(void* const* d_in, const int* in_sizes, int n_in,
                              void* d_out, int out_size, void* d_ws, size_t ws_size,
                              hipStream_t stream) {
  const float* x      = (const float*)d_in[0];
  const int*   ei     = (const int*)d_in[1];
  const float* W0     = (const float*)d_in[2];
  const float* a_src0 = (const float*)d_in[3];
  const float* a_dst0 = (const float*)d_in[4];
  const float* b0     = (const float*)d_in[5];
  const float* gamma0 = (const float*)d_in[6];
  const float* beta0  = (const float*)d_in[7];
  const float* W1     = (const float*)d_in[8];
  const float* a_src1 = (const float*)d_in[9];
  const float* a_dst1 = (const float*)d_in[10];
  const float* b1     = (const float*)d_in[11];
  const float* gamma1 = (const float*)d_in[12];
  const float* beta1  = (const float*)d_in[13];
  const float* Wc     = (const float*)d_in[14];
  const float* bc     = (const float*)d_in[15];
  float* out = (float*)d_out;

  char* ws = (char*)d_ws;
  size_t o = 0;
  auto alloc = [&](size_t bytes) { char* p = ws + o; o = (o + bytes + 255) & ~(size_t)255; return p; };
  int*   flag    = (int*)  alloc(4);
  int*   done    = (int*)  alloc(4);
  int*   src32   = (int*)  alloc((size_t)N_EDGES * 4);
  int*   dst32   = (int*)  alloc((size_t)N_EDGES * 4);
  int*   counts  = (int*)  alloc((size_t)N_NODES * 4);
  int*   excl    = (int*)  alloc((size_t)N_NODES * 4);
  int*   bsum    = (int*)  alloc(256 * 4);
  int*   bsum_s  = (int*)  alloc(256 * 4);
  int*   off     = (int*)  alloc((size_t)(N_NODES + 1) * 4);
  int*   cursor  = (int*)  alloc((size_t)N_NODES * 4);
  int*   csr     = (int*)  alloc((size_t)E_TOT * 4);
  float* s_src   = (float*)alloc((size_t)N_NODES * NHEAD * 4);
  float* s_dst   = (float*)alloc((size_t)N_NODES * NHEAD * 4);
  float* partial = (float*)alloc((size_t)STAT_B * 1024 * 4);
  float* scale   = (float*)alloc(C * 4);
  float* shift   = (float*)alloc(C * 4);
  unsigned short* bt0  = (unsigned short*)alloc((size_t)NHEAD * HID * IN_CH * 2);
  unsigned short* bt1  = (unsigned short*)alloc((size_t)NHEAD * HID * HID * 2);
  unsigned short* h16a = (unsigned short*)alloc((size_t)N_NODES * C * 2);
  unsigned short* h16b = (unsigned short*)alloc((size_t)N_NODES * C * 2);

  const int GE = (N_EDGES + 255) / 256;      // 3125
  const int GN = (N_NODES + 255) / 256;      // 196
  const int GW = (N_NODES + 3) / 4;          // 12500
  const int GR = (N_NODES + 63) / 64;        // 782

  // CSR build (R5 structure — measured best non-aggregate config)
  k_init<<<GN, 256, 0, stream>>>(ei, counts, flag, done);
  k_extract_count<<<GE, 256, 0, stream>>>(ei, flag, src32, dst32, counts);
  k_transpose_both<<<384, 256, 0, stream>>>(W0, W1, bt0, bt1);
  k_scan12<<<GN, 256, 0, stream>>>(counts, excl, bsum, done, bsum_s);
  k_scan3<<<GN, 256, 0, stream>>>(excl, bsum_s, off, cursor, csr);
  k_scatter_edges<<<GE, 256, 0, stream>>>(src32, dst32, cursor, csr);

  // ----- layer 0 -----
  k_gemm0<<<GR, 256, 0, stream>>>(x, bt0, a_src0, a_dst0, h16a, s_src, s_dst);
  k_aggregate<<<GW, 256, 0, stream>>>(h16a, s_src, s_dst, off, csr, b0, h16b);
  k_bn_stats<<<STAT_B, 256, 0, stream>>>(h16b, partial);
  k_bn_finalize<<<1, 512, 0, stream>>>(partial, gamma0, beta0, scale, shift);

  // ----- layer 1 (BN0+ELU fused into GEMM1 A-staging) -----
  k_gemm1<<<dim3(GR, NHEAD), 256, 0, stream>>>(h16b, bt1, scale, shift, a_src1, a_dst1, h16a, s_src, s_dst);
  k_aggregate<<<GW, 256, 0, stream>>>(h16a, s_src, s_dst, off, csr, b1, h16b);
  k_bn_stats<<<STAT_B, 256, 0, stream>>>(h16b, partial);
  k_bn_finalize<<<1, 512, 0, stream>>>(partial, gamma1, beta1, scale, shift);

  // ----- classifier (BN1+ELU fused) -----
  k_final<<<GW, 256, 0, stream>>>(h16b, scale, shift, Wc, bc, out);
}